// Round 24
// baseline (190.439 us; speedup 1.0000x reference)
//
#include <hip/hip_runtime.h>

#define B_   128
#define L_   196
#define ENC_ 2048
#define DEC_ 512
#define ATT_ 512
#define M_   (B_ * L_)   // 25088

typedef _Float16 f16x8 __attribute__((ext_vector_type(8)));
typedef __fp16   h16x2 __attribute__((ext_vector_type(2)));
typedef float    f32x4 __attribute__((ext_vector_type(4)));

// Raw barrier: order LDS ops (lgkmcnt) but do NOT drain vmcnt.
#define FENCE_LDS_BARRIER()                                        \
    do {                                                           \
        asm volatile("s_waitcnt lgkmcnt(0)" ::: "memory");         \
        __builtin_amdgcn_s_barrier();                              \
        __builtin_amdgcn_sched_barrier(0);                         \
    } while (0)

__device__ __forceinline__ void gload16(const _Float16* g, _Float16* l) {
    __builtin_amdgcn_global_load_lds(
        (const __attribute__((address_space(1))) void*)g,
        (__attribute__((address_space(3))) void*)l, 16, 0, 0);
}

// ---------------- ws layout ----------------
// [0,        262144)  dec_map f32 [128][512]
// [262144,  2359296)  WeTs    f16 tiled [nt=4][kt=64][k8=4][row=128] x f16x8
// [2359296, 2760704)  partial f32 [4][25088]

// We [2048][512] fp32 -> WeTs tiled-f16 (R8 layout).
__global__ void wets_kernel(const float* __restrict__ We, _Float16* __restrict__ WeTs) {
    int u = blockIdx.x * 256 + threadIdx.x;     // 131072 units
    int row = u & 127;
    int k8  = (u >> 7) & 3;
    int kt  = (u >> 9) & 63;
    int nt  = u >> 15;
    int n  = nt * 128 + row;
    int k0 = kt * 32 + k8 * 8;
    f16x8 h;
#pragma unroll
    for (int j = 0; j < 8; ++j) h[j] = (_Float16)We[(k0 + j) * ATT_ + n];
    *reinterpret_cast<f16x8*>(WeTs + (size_t)u * 8) = h;
}

__global__ void decmap_kernel(const float* __restrict__ dh, const float* __restrict__ Wd,
                              const float* __restrict__ bd, float* __restrict__ dec) {
    int b = blockIdx.x;       // 128
    int a = threadIdx.x;      // 512
    float acc = bd[a];
    const float* dhp = dh + b * DEC_;
#pragma unroll 8
    for (int k = 0; k < DEC_; ++k) acc += dhp[k] * Wd[k * ATT_ + a];
    dec[b * ATT_ + a] = acc;
}

// Fused GEMM: 64x128 tile, BK=32, 128 threads = 2 waves (each 64x64, acc 64
// regs). DESYNC thesis (R8=3 blocks/CU best 12.3 cy/MFMA; 1-2 block variants
// 20+): independent blocks overlap each other's barrier stalls. This config:
// LDS 24.5KB -> 6 blocks/CU resident = 6 independent barrier groups, 12
// waves/CU. Grid 1568 (392 mtile x 4 ntile, 8x196 exact XCD chunking).
// Schedule = R22's audited counted-vmcnt pipeline: A reg-staged 2 static
// sets (write-late drains only last-phase A loads, in-order); B DMA 1-ahead
// via global_load_lds (0 regs); end-of-phase vmcnt(4) drains B while leaving
// this phase's 4 A loads in flight; lgkm-only fences.
// launch_bounds(128,3): 3 waves/EU -> 170-reg cap (arch ~150 incl. 64 acc).
__global__ __launch_bounds__(128, 3)
void gemm_score_kernel(const float* __restrict__ enc,
                       const _Float16* __restrict__ WeTs,
                       const float* __restrict__ be,
                       const float* __restrict__ wa,
                       const float* __restrict__ dec,
                       float* __restrict__ partial) {
    __shared__ _Float16 As[2][2048];     // 4KB each: [k8=4][row=64] units swz
    __shared__ _Float16 Bs[2][4096];     // 8KB each: [k8=4][col=128] linear
    __shared__ float red[2][64];

    // XCD chunk: 1568 = 8*196 exact.
    int bid = blockIdx.x;
    int sid = (bid & 7) * 196 + (bid >> 3);          // bijective on [0,1568)
    int mtile = sid >> 2;                            // 0..391 (64-row tiles)
    int ntile = sid & 3;                             // 0..3  (128-col tiles)

    int tid  = threadIdx.x;
    int lane = tid & 63;
    int wn   = tid >> 6;                             // 2 waves split N
    int l15 = lane & 15, lg = lane >> 4;

    // A staging: thread -> row = tid>>1 (0..63), h = tid&1 (16 floats)
    int arow = tid >> 1;
    int h    = tid & 1;
    const float* ag = enc + (size_t)(mtile * 64 + arow) * ENC_ + h * 16;
    int wa0 = ((2 * h) * 64 + (arow ^ (4 * h))) * 8;         // unit(c8=2h)
    int wa1 = ((2 * h + 1) * 64 + (arow ^ (4 * h + 2))) * 8; // unit(c8=2h+1)

    // B DMA source: WeTs units (ntile, kt, k8, row): per-kt 512 units
    const _Float16* bsrc = WeTs + (size_t)ntile * 64 * 4096;

    // frag read half-offsets
    int afo = (lg * 64 + (l15 ^ (2 * lg))) * 8;      // + mi*128
    int bfo = (lg * 128 + wn * 64 + l15) * 8;        // + ni*128

    // A staging register sets — statically named (rule #20)
    float4 areg0[4], areg1[4];

    f32x4 acc[4][4];
#pragma unroll
    for (int mi = 0; mi < 4; ++mi)
#pragma unroll
        for (int ni = 0; ni < 4; ++ni) acc[mi][ni] = (f32x4){0.f, 0.f, 0.f, 0.f};

#define DEF_LOADA(S)                                                     \
    auto loadA##S = [&](int kt) {                                        \
        const float* a = ag + kt * 32;                                   \
        areg##S[0] = *reinterpret_cast<const float4*>(a);                \
        areg##S[1] = *reinterpret_cast<const float4*>(a + 4);            \
        areg##S[2] = *reinterpret_cast<const float4*>(a + 8);            \
        areg##S[3] = *reinterpret_cast<const float4*>(a + 12);           \
    }
    DEF_LOADA(0); DEF_LOADA(1);
#undef DEF_LOADA

#define DEF_WRITEA(S)                                                    \
    auto writeA##S = [&](int buf) {                                      \
        _Float16* Ap = As[buf];                                          \
        union { h16x2 h2[4]; f16x8 h8; } cv;                             \
        cv.h2[0] = __builtin_amdgcn_cvt_pkrtz(areg##S[0].x, areg##S[0].y); \
        cv.h2[1] = __builtin_amdgcn_cvt_pkrtz(areg##S[0].z, areg##S[0].w); \
        cv.h2[2] = __builtin_amdgcn_cvt_pkrtz(areg##S[1].x, areg##S[1].y); \
        cv.h2[3] = __builtin_amdgcn_cvt_pkrtz(areg##S[1].z, areg##S[1].w); \
        *reinterpret_cast<f16x8*>(Ap + wa0) = cv.h8;                     \
        cv.h2[0] = __builtin_amdgcn_cvt_pkrtz(areg##S[2].x, areg##S[2].y); \
        cv.h2[1] = __builtin_amdgcn_cvt_pkrtz(areg##S[2].z, areg##S[2].w); \
        cv.h2[2] = __builtin_amdgcn_cvt_pkrtz(areg##S[3].x, areg##S[3].y); \
        cv.h2[3] = __builtin_amdgcn_cvt_pkrtz(areg##S[3].z, areg##S[3].w); \
        *reinterpret_cast<f16x8*>(Ap + wa1) = cv.h8;                     \
    }
    DEF_WRITEA(0); DEF_WRITEA(1);
#undef DEF_WRITEA

    // 8 DMA instructions stage one 32x128 f16 B tile (512 units)
    auto dmab = [&](int buf, int kt) {
        const _Float16* s = bsrc + (size_t)kt * 4096;
#pragma unroll
        for (int j = 0; j < 4; ++j)
            gload16(s + (j * 128 + tid) * 8, &Bs[buf][(j * 128 + tid) * 8]);
    };
    auto compute = [&](int buf) {
        const _Float16* Ap = As[buf];
        const _Float16* Bp = Bs[buf];
        f16x8 af[4], bf[4];
#pragma unroll
        for (int mi = 0; mi < 4; ++mi)
            af[mi] = *reinterpret_cast<const f16x8*>(Ap + afo + mi * 128);
#pragma unroll
        for (int ni = 0; ni < 4; ++ni)
            bf[ni] = *reinterpret_cast<const f16x8*>(Bp + bfo + ni * 128);
#pragma unroll
        for (int mi = 0; mi < 4; ++mi)
#pragma unroll
            for (int ni = 0; ni < 4; ++ni)
                acc[mi][ni] = __builtin_amdgcn_mfma_f32_16x16x32_f16(
                    af[mi], bf[ni], acc[mi][ni], 0, 0, 0);
    };

    // prologue: B(0)->buf0 [8 ops]; A(0)->set0, A(1)->set1 [8 ops];
    // writeA0 reg-dep drains <=A(0) (incl. DMA B(0)); vmcnt(4) leaves A(1).
    dmab(0, 0);
    __builtin_amdgcn_sched_barrier(0);
    loadA0(0);
    loadA1(1);
    writeA0(0);
    asm volatile("s_waitcnt vmcnt(4)" ::: "memory");
    __builtin_amdgcn_sched_barrier(0);
    FENCE_LDS_BARRIER();

    // phase k: DMA B(k+1)->buf (k+1)&1 [8]; loadA(k+2)->set k&1 [4];
    // compute bufs k&1; writeA set (k+1)&1 (holds A(k+1), loaded last phase
    // -> in-order drain stops before this phase's ops); vmcnt(4) drains
    // B(k+1), leaves the 4 A loads; lgkm fence.
    for (int k2 = 0; k2 < 32; ++k2) {
        int k = k2 * 2;
        {
            int kb = k + 1;
            int ka = k + 2 < 64 ? k + 2 : 63;
            dmab(1, kb);
            __builtin_amdgcn_sched_barrier(0);
            loadA0(ka);
            __builtin_amdgcn_sched_barrier(0);
            compute(0);
            __builtin_amdgcn_sched_barrier(0);
            writeA1(1);
            asm volatile("s_waitcnt vmcnt(4)" ::: "memory");
            __builtin_amdgcn_sched_barrier(0);
            FENCE_LDS_BARRIER();
        }
        {
            int kb = k + 2 < 64 ? k + 2 : 63;
            int ka = k + 3 < 64 ? k + 3 : 63;
            dmab(0, kb);
            __builtin_amdgcn_sched_barrier(0);
            loadA1(ka);
            __builtin_amdgcn_sched_barrier(0);
            compute(1);
            __builtin_amdgcn_sched_barrier(0);
            writeA0(0);
            asm volatile("s_waitcnt vmcnt(4)" ::: "memory");
            __builtin_amdgcn_sched_barrier(0);
            FENCE_LDS_BARRIER();
        }
    }

    // Epilogue: x = acc + be[n] + dec[b][n]; rowsum += tanh(x)*wa[n]
    float rsum[4][4];
#pragma unroll
    for (int mi = 0; mi < 4; ++mi)
#pragma unroll
        for (int j = 0; j < 4; ++j) rsum[mi][j] = 0.f;

    int rb = mtile * 64;
#pragma unroll
    for (int ni = 0; ni < 4; ++ni) {
        int n = ntile * 128 + wn * 64 + ni * 16 + l15;
        float wav = wa[n];
        float bev = be[n];
#pragma unroll
        for (int mi = 0; mi < 4; ++mi) {
#pragma unroll
            for (int j = 0; j < 4; ++j) {
                int row = rb + mi * 16 + lg * 4 + j;    // C/D: col=lane&15, row=(lane>>4)*4+reg
                int b = row / L_;
                float x = acc[mi][ni][j] + bev + dec[b * ATT_ + n];
                float e = __expf(2.0f * x);
                float t = 1.0f - 2.0f / (e + 1.0f);     // tanh(x), inf-safe
                rsum[mi][j] += t * wav;
            }
        }
    }
#pragma unroll
    for (int mi = 0; mi < 4; ++mi) {
#pragma unroll
        for (int j = 0; j < 4; ++j) {
            float v = rsum[mi][j];
            v += __shfl_xor(v, 1);
            v += __shfl_xor(v, 2);
            v += __shfl_xor(v, 4);
            v += __shfl_xor(v, 8);
            if (l15 == 0) red[wn][mi * 16 + lg * 4 + j] = v;
        }
    }
    __syncthreads();
    if (tid < 64)
        partial[(size_t)ntile * M_ + mtile * 64 + tid] = red[0][tid] + red[1][tid];
}

// softmax over L per batch row; sums the 4 ntile partials. ba cancels.
__global__ void softmax_kernel(const float* __restrict__ partial, float* __restrict__ alphas) {
    int b = blockIdx.x, t = threadIdx.x;     // 128 blocks x 256 threads
    int lane = t & 63, wid = t >> 6;
    __shared__ float red[4];
    float s = 0.f, val = -1e30f;
    if (t < L_) {
        int r = b * L_ + t;
        s = partial[r] + partial[M_ + r] + partial[2 * M_ + r] + partial[3 * M_ + r];
        val = s;
    }
    float m = val;
#pragma unroll
    for (int off = 1; off < 64; off <<= 1) m = fmaxf(m, __shfl_xor(m, off));
    if (lane == 0) red[wid] = m;
    __syncthreads();
    m = fmaxf(fmaxf(red[0], red[1]), fmaxf(red[2], red[3]));
    float e = (t < L_) ? __expf(s - m) : 0.f;
    float sum = e;
#pragma unroll
    for (int off = 1; off < 64; off <<= 1) sum += __shfl_xor(sum, off);
    __syncthreads();
    if (lane == 0) red[wid] = sum;
    __syncthreads();
    sum = red[0] + red[1] + red[2] + red[3];
    if (t < L_) alphas[b * L_ + t] = e / sum;
}

// context[b][e] = sum_l alphas[b][l] * enc[b][l][e]
__global__ void context_kernel(const float* __restrict__ enc, const float* __restrict__ alphas,
                               float* __restrict__ ctx) {
    int b = blockIdx.x >> 2;                  // 128 b x 4 e-chunks = 512 blocks
    int ec = blockIdx.x & 3;
    int e = ec * 512 + threadIdx.x * 2;
    const float* ep = enc + (size_t)b * L_ * ENC_ + e;
    const float* ap = alphas + b * L_;
    float ax = 0.f, ay = 0.f;
#pragma unroll 4
    for (int l = 0; l < L_; ++l) {
        float a = ap[l];
        float2 v = *reinterpret_cast<const float2*>(ep + (size_t)l * ENC_);
        ax += a * v.x;
        ay += a * v.y;
    }
    float2 r; r.x = ax; r.y = ay;
    *reinterpret_cast<float2*>(&ctx[b * ENC_ + e]) = r;
}

extern "C" void kernel_launch(void* const* d_in, const int* in_sizes, int n_in,
                              void* d_out, int out_size, void* d_ws, size_t ws_size,
                              hipStream_t stream) {
    const float* enc = (const float*)d_in[0];
    const float* dh  = (const float*)d_in[1];
    const float* We  = (const float*)d_in[2];
    const float* be  = (const float*)d_in[3];
    const float* Wd  = (const float*)d_in[4];
    const float* bd  = (const float*)d_in[5];
    const float* wa  = (const float*)d_in[6];
    // d_in[7] = ba: shifts all scores equally -> cancels in softmax, unused.

    float* out    = (float*)d_out;
    float* ctx    = out;               // [128][2048]
    float* alphas = out + B_ * ENC_;   // [128][196]

    char* ws = (char*)d_ws;
    float*    dec     = (float*)ws;                            // 256 KiB
    _Float16* WeTs    = (_Float16*)(ws + 262144);              // 2 MiB
    float*    partial = (float*)(ws + 2359296);                // 392 KiB

    hipLaunchKernelGGL(wets_kernel,       dim3(512),  dim3(256), 0, stream, We, WeTs);
    hipLaunchKernelGGL(decmap_kernel,     dim3(128),  dim3(512), 0, stream, dh, Wd, bd, dec);
    hipLaunchKernelGGL(gemm_score_kernel, dim3(1568), dim3(128), 0, stream, enc, WeTs, be, wa, dec, partial);
    hipLaunchKernelGGL(softmax_kernel,    dim3(128),  dim3(256), 0, stream, partial, alphas);
    hipLaunchKernelGGL(context_kernel,    dim3(512),  dim3(256), 0, stream, enc, alphas, ctx);
}